// Round 1
// baseline (22453.345 us; speedup 1.0000x reference)
//
#include <hip/hip_runtime.h>
#include <math.h>

#define BATCH_N 32
#define SEQ_N   512
#define HID     1024   // hidden size == 4R == input size == 1024 (all equal here)

#define NWG   256      // scan workgroups (1 per CU, co-resident)
#define NTHR  512      // threads per scan WG (8 waves)

// d_ws layout (floats): [0,32768) h_buf ; [32768,65536) g_buf ; then flags (uint)
// flags layout (uints): [0..1023] group counters (stride 32), [1024] global cnt, [1056] gen

// ---------------------------------------------------------------- init
__global__ void init_kernel(float* bufs, unsigned* flags) {
    int i = blockIdx.x * blockDim.x + threadIdx.x;
    if (i < 2 * BATCH_N * HID) bufs[i] = 0.0f;   // h_buf + g_buf
    if (i < 1088) flags[i] = 0u;
}

// ---------------------------------------------------------------- xb = x @ b
// X: (16384,1024) row-major, Bw: (1024,1024) row-major, XB: (16384,1024)
__global__ __launch_bounds__(256) void xb_gemm(const float* __restrict__ X,
                                               const float* __restrict__ Bw,
                                               float* __restrict__ XB) {
    __shared__ float xs[16][132];   // [k][m] (BM=128, +4 pad keeps 16B align)
    __shared__ float bs[16][132];   // [k][n] (BN=128)
    const int bm = blockIdx.x >> 3;       // 128 m-tiles
    const int bn = blockIdx.x & 7;        // 8 n-tiles
    const int m0 = bm * 128, n0 = bn * 128;
    const int tid = threadIdx.x;
    const int tx = tid & 15, ty = tid >> 4;
    float acc[8][8];
#pragma unroll
    for (int i = 0; i < 8; ++i)
#pragma unroll
        for (int j = 0; j < 8; ++j) acc[i][j] = 0.f;

    for (int k0 = 0; k0 < 1024; k0 += 16) {
#pragma unroll
        for (int p = 0; p < 2; ++p) {   // stage X tile (128m x 16k)
            int f = tid + p * 256;      // 0..511
            int m = f >> 2, kq = f & 3;
            float4 v = *(const float4*)&X[(size_t)(m0 + m) * 1024 + k0 + kq * 4];
            xs[kq * 4 + 0][m] = v.x; xs[kq * 4 + 1][m] = v.y;
            xs[kq * 4 + 2][m] = v.z; xs[kq * 4 + 3][m] = v.w;
        }
#pragma unroll
        for (int p = 0; p < 2; ++p) {   // stage B tile (16k x 128n)
            int f = tid + p * 256;
            int k = f >> 5, n = (f & 31) * 4;
            float4 v = *(const float4*)&Bw[(size_t)(k0 + k) * 1024 + n0 + n];
            *(float4*)&bs[k][n] = v;
        }
        __syncthreads();
#pragma unroll
        for (int k = 0; k < 16; ++k) {
            float xv[8], bv[8];
            *(float4*)&xv[0] = *(const float4*)&xs[k][ty * 8];
            *(float4*)&xv[4] = *(const float4*)&xs[k][ty * 8 + 4];
            *(float4*)&bv[0] = *(const float4*)&bs[k][tx * 8];
            *(float4*)&bv[4] = *(const float4*)&bs[k][tx * 8 + 4];
#pragma unroll
            for (int i = 0; i < 8; ++i)
#pragma unroll
                for (int j = 0; j < 8; ++j) acc[i][j] += xv[i] * bv[j];
        }
        __syncthreads();
    }
#pragma unroll
    for (int i = 0; i < 8; ++i)
#pragma unroll
        for (int j = 0; j < 8; j += 4) {
            float4 v = make_float4(acc[i][j], acc[i][j + 1], acc[i][j + 2], acc[i][j + 3]);
            *(float4*)&XB[(size_t)(m0 + ty * 8 + i) * 1024 + n0 + tx * 8 + j] = v;
        }
}

// ---------------------------------------------------------------- grid barrier
__device__ __forceinline__ void grid_barrier(unsigned* flags, int wg, unsigned target) {
    __syncthreads();
    if (threadIdx.x == 0) {
        __threadfence();   // make this WG's data stores device-visible
        unsigned* gcnt = flags + ((wg >> 3) << 5);   // 32 groups of 8, own cacheline
        unsigned* cnt  = flags + 1024;
        unsigned* gen  = flags + 1056;
        bool is_last = false;
        unsigned a = __hip_atomic_fetch_add(gcnt, 1u, __ATOMIC_ACQ_REL, __HIP_MEMORY_SCOPE_AGENT);
        if (a == 7u) {
            __hip_atomic_store(gcnt, 0u, __ATOMIC_RELAXED, __HIP_MEMORY_SCOPE_AGENT);
            unsigned b = __hip_atomic_fetch_add(cnt, 1u, __ATOMIC_ACQ_REL, __HIP_MEMORY_SCOPE_AGENT);
            if (b == 31u) {
                __hip_atomic_store(cnt, 0u, __ATOMIC_RELAXED, __HIP_MEMORY_SCOPE_AGENT);
                __hip_atomic_store(gen, target, __ATOMIC_RELEASE, __HIP_MEMORY_SCOPE_AGENT);
                is_last = true;
            }
        }
        if (!is_last) {
            while (__hip_atomic_load(gen, __ATOMIC_RELAXED, __HIP_MEMORY_SCOPE_AGENT) < target) {
                __builtin_amdgcn_s_sleep(1);
            }
        }
        __threadfence();   // acquire side: invalidate stale caches before data reads
    }
    __syncthreads();
}

// ---------------------------------------------------------------- persistent scan
// A: (1024, 1024) = (H, 4R); CTm: (1024, 1024) = (4R, H)
// XBH: (B, S, 1024): holds xb on entry, hidden_seq on exit (in-place, step-ordered)
__global__ __launch_bounds__(NTHR, 1) void scan_kernel(
    const float* __restrict__ A, const float* __restrict__ CTm,
    float* __restrict__ XBH, float* __restrict__ h_buf, float* __restrict__ g_buf,
    float* __restrict__ ht_out, float* __restrict__ ct_out, unsigned* flags) {
    extern __shared__ float lds[];            // 32768 weight floats + 2048 red floats
    float4* a_sl4  = (float4*)lds;            // [c:16][iq:256] swizzled col-major cols of A
    float4* ct_sl4 = (float4*)(lds + 16384);  // same for CT
    float* red = lds + 32768;                 // [2048] reduction scratch

    const int wg  = blockIdx.x;
    const int bg  = wg >> 6;           // 4 batch groups x 8 batches
    const int sg  = wg & 63;           // 64 column slices x 16 cols
    const int c0  = sg * 16;
    const int b0g = bg * 8;
    const int tid = threadIdx.x;

    // ---- preload weight slices into LDS (swizzled: float4 index iq -> iq ^ (c&7)) ----
    {
        const int cc = tid & 15;
        const int i0 = tid >> 4;       // 0..31
        const size_t gcol = (size_t)(c0 + cc);
        for (int ib = 0; ib < 1024; ib += 32) {
            int i = ib + i0;
            int fi = cc * 1024 + (((i >> 2) ^ (cc & 7)) << 2) + (i & 3);
            lds[fi]         = A[(size_t)i * 1024 + gcol];
            lds[16384 + fi] = CTm[(size_t)i * 1024 + gcol];
        }
    }
    __syncthreads();

    // phase A mapping: wave = kq (8 x 128-i ranges); lanes: bp=(tid>>4)&3 (2 batches), c=tid&15
    const int a_kq = tid >> 6;
    const int a_bp = (tid >> 4) & 3;
    const int a_c  = tid & 15;
    const int a_b0 = b0g + a_bp * 2;
    // phase B mapping: wave: rq=tid>>7 (4 r-quarters), gp=(tid>>6)&1 (gate pair); lanes: bp, j
    const int p_rq = tid >> 7;
    const int p_gp = (tid >> 6) & 1;
    const int p_bp = (tid >> 4) & 3;
    const int p_j  = tid & 15;
    const int p_b0 = b0g + p_bp * 2;
    // reducer mapping (tid < 64)
    const int r_bp = (tid >> 4) & 3;
    const int r_cj = tid & 15;
    const int r_b0 = b0g + r_bp * 2;

    float creg0 = 0.f, creg1 = 0.f;
    unsigned bar = 0;

    for (int t = 0; t < SEQ_N; ++t) {
        // ---------------- phase A: g[b, c0..c0+15] = (h @ A_slice) * xb[:, t, slice]
        {
            const float4* h0 = (const float4*)(h_buf + (size_t)a_b0 * HID);
            const float4* h1 = (const float4*)(h_buf + (size_t)(a_b0 + 1) * HID);
            const float4* acol = a_sl4 + a_c * 256;
            const int swz = a_c & 7;
            const int iqb = a_kq * 32;       // 32 float4 = 128 i per wave
            float a0e = 0.f, a0o = 0.f, a1e = 0.f, a1o = 0.f;
#pragma unroll
            for (int ii = 0; ii < 32; ii += 2) {
                {
                    int iq = iqb + ii;
                    float4 av = acol[iq ^ swz];
                    float4 v0 = h0[iq]; float4 v1 = h1[iq];
                    a0e += av.x * v0.x + av.y * v0.y + av.z * v0.z + av.w * v0.w;
                    a1e += av.x * v1.x + av.y * v1.y + av.z * v1.z + av.w * v1.w;
                }
                {
                    int iq = iqb + ii + 1;
                    float4 av = acol[iq ^ swz];
                    float4 v0 = h0[iq]; float4 v1 = h1[iq];
                    a0o += av.x * v0.x + av.y * v0.y + av.z * v0.z + av.w * v0.w;
                    a1o += av.x * v1.x + av.y * v1.y + av.z * v1.z + av.w * v1.w;
                }
            }
            red[tid]       = a0e + a0o;
            red[512 + tid] = a1e + a1o;
            __syncthreads();
            if (tid < 64) {
                float s0 = 0.f, s1 = 0.f;
#pragma unroll
                for (int k = 0; k < 8; ++k) {
                    s0 += red[k * 64 + tid];
                    s1 += red[512 + k * 64 + tid];
                }
                int col = c0 + r_cj;
                float xb0 = XBH[((size_t)r_b0 * SEQ_N + t) * 1024 + col];
                float xb1 = XBH[((size_t)(r_b0 + 1) * SEQ_N + t) * 1024 + col];
                g_buf[(size_t)r_b0 * 1024 + col]       = s0 * xb0;
                g_buf[(size_t)(r_b0 + 1) * 1024 + col] = s1 * xb1;
            }
        }
        grid_barrier(flags, wg, ++bar);

        // ---------------- phase B: gates = g @ ct3 per gate; LSTM cell update
        {
            const float4* g0 = (const float4*)(g_buf + (size_t)p_b0 * 1024);
            const float4* g1 = (const float4*)(g_buf + (size_t)(p_b0 + 1) * 1024);
            const float4* ccol = ct_sl4 + p_j * 256;
            const int swz = p_j & 7;
#pragma unroll
            for (int gg = 0; gg < 2; ++gg) {
                const int gate = p_gp * 2 + gg;
                const int base = gate * 64 + p_rq * 16;   // 16 float4 per (gate, rq)
                float t0e = 0.f, t0o = 0.f, t1e = 0.f, t1o = 0.f;
#pragma unroll
                for (int ii = 0; ii < 16; ii += 2) {
                    {
                        int iq = base + ii;
                        float4 cv = ccol[iq ^ swz];
                        float4 u0 = g0[iq]; float4 u1 = g1[iq];
                        t0e += cv.x * u0.x + cv.y * u0.y + cv.z * u0.z + cv.w * u0.w;
                        t1e += cv.x * u1.x + cv.y * u1.y + cv.z * u1.z + cv.w * u1.w;
                    }
                    {
                        int iq = base + ii + 1;
                        float4 cv = ccol[iq ^ swz];
                        float4 u0 = g0[iq]; float4 u1 = g1[iq];
                        t0o += cv.x * u0.x + cv.y * u0.y + cv.z * u0.z + cv.w * u0.w;
                        t1o += cv.x * u1.x + cv.y * u1.y + cv.z * u1.z + cv.w * u1.w;
                    }
                }
                int bpj = tid & 63;
                red[(((gate << 2) | p_rq) << 6) | bpj]        = t0e + t0o;
                red[1024 + ((((gate << 2) | p_rq) << 6) | bpj)] = t1e + t1o;
            }
            __syncthreads();
            if (tid < 64) {
                float pre[2][4];
#pragma unroll
                for (int bb = 0; bb < 2; ++bb)
#pragma unroll
                    for (int gate = 0; gate < 4; ++gate) {
                        int o = bb * 1024 + gate * 256;
                        pre[bb][gate] = red[o + tid] + red[o + 64 + tid] +
                                        red[o + 128 + tid] + red[o + 192 + tid];
                    }
                float f0 = 1.f / (1.f + __expf(-pre[0][0]));
                float i0 = 1.f / (1.f + __expf(-pre[0][1]));
                float g0v = tanhf(pre[0][2]);
                float o0 = 1.f / (1.f + __expf(-pre[0][3]));
                creg0 = f0 * creg0 + i0 * g0v;
                float hh0 = o0 * tanhf(creg0);
                float f1 = 1.f / (1.f + __expf(-pre[1][0]));
                float i1 = 1.f / (1.f + __expf(-pre[1][1]));
                float g1v = tanhf(pre[1][2]);
                float o1 = 1.f / (1.f + __expf(-pre[1][3]));
                creg1 = f1 * creg1 + i1 * g1v;
                float hh1 = o1 * tanhf(creg1);
                int jg = c0 + r_cj;
                h_buf[(size_t)r_b0 * HID + jg]       = hh0;
                h_buf[(size_t)(r_b0 + 1) * HID + jg] = hh1;
                XBH[((size_t)r_b0 * SEQ_N + t) * 1024 + jg]       = hh0;  // hidden_seq out
                XBH[((size_t)(r_b0 + 1) * SEQ_N + t) * 1024 + jg] = hh1;
                if (t == SEQ_N - 1) {
                    ht_out[(size_t)r_b0 * HID + jg]       = hh0;
                    ht_out[(size_t)(r_b0 + 1) * HID + jg] = hh1;
                    ct_out[(size_t)r_b0 * HID + jg]       = creg0;
                    ct_out[(size_t)(r_b0 + 1) * HID + jg] = creg1;
                }
            }
        }
        grid_barrier(flags, wg, ++bar);
    }
}

// ---------------------------------------------------------------- launch
extern "C" void kernel_launch(void* const* d_in, const int* in_sizes, int n_in,
                              void* d_out, int out_size, void* d_ws, size_t ws_size,
                              hipStream_t stream) {
    const float* X   = (const float*)d_in[0];   // (32, 512, 1024)
    const float* A   = (const float*)d_in[1];   // (1024, 1024)
    const float* Bw  = (const float*)d_in[2];   // (1024, 1024)
    const float* CTm = (const float*)d_in[3];   // (1024, 1024)

    float* out    = (float*)d_out;
    float* XBH    = out;                                    // (B,S,1024): xb then hidden
    float* ht_out = out + (size_t)BATCH_N * SEQ_N * HID;    // (B,H)
    float* ct_out = ht_out + BATCH_N * HID;                 // (B,H)

    float* h_buf = (float*)d_ws;
    float* g_buf = h_buf + BATCH_N * HID;
    unsigned* flags = (unsigned*)(h_buf + 2 * BATCH_N * HID);

    static int attr_set = 0;
    (void)hipFuncSetAttribute((const void*)scan_kernel,
                              hipFuncAttributeMaxDynamicSharedMemorySize, 139264);
    (void)attr_set;

    init_kernel<<<dim3(256), dim3(256), 0, stream>>>(h_buf, flags);
    xb_gemm<<<dim3(1024), dim3(256), 0, stream>>>(X, Bw, XBH);
    scan_kernel<<<dim3(NWG), dim3(NTHR), 139264, stream>>>(A, CTm, XBH, h_buf, g_buf,
                                                           ht_out, ct_out, flags);
}

// Round 2
// 5404.287 us; speedup vs baseline: 4.1547x; 4.1547x over previous
//
#include <hip/hip_runtime.h>
#include <math.h>

#define NTHR 512

// ---------------------------------------------------------------- uncached ops
__device__ __forceinline__ void st_uc(float* p, float v) {
    asm volatile("global_store_dword %0, %1, off sc0 sc1" :: "v"(p), "v"(v) : "memory");
}

// ---------------------------------------------------------------- init
__global__ void init_kernel(float* bufs, unsigned* flags) {
    int i = blockIdx.x * blockDim.x + threadIdx.x;
    if (i < 65536) bufs[i] = 0.0f;       // h_buf (32K) + g_buf (32K)
    if (i < 4096) flags[i] = 0u;         // 4 groups x 1024 uints
}

// ---------------------------------------------------------------- xb = x @ b
__global__ __launch_bounds__(256) void xb_gemm(const float* __restrict__ X,
                                               const float* __restrict__ Bw,
                                               float* __restrict__ XB) {
    __shared__ float xs[16][132];
    __shared__ float bs[16][132];
    const int bm = blockIdx.x >> 3;
    const int bn = blockIdx.x & 7;
    const int m0 = bm * 128, n0 = bn * 128;
    const int tid = threadIdx.x;
    const int tx = tid & 15, ty = tid >> 4;
    float acc[8][8];
#pragma unroll
    for (int i = 0; i < 8; ++i)
#pragma unroll
        for (int j = 0; j < 8; ++j) acc[i][j] = 0.f;

    for (int k0 = 0; k0 < 1024; k0 += 16) {
#pragma unroll
        for (int p = 0; p < 2; ++p) {
            int f = tid + p * 256;
            int m = f >> 2, kq = f & 3;
            float4 v = *(const float4*)&X[(size_t)(m0 + m) * 1024 + k0 + kq * 4];
            xs[kq * 4 + 0][m] = v.x; xs[kq * 4 + 1][m] = v.y;
            xs[kq * 4 + 2][m] = v.z; xs[kq * 4 + 3][m] = v.w;
        }
#pragma unroll
        for (int p = 0; p < 2; ++p) {
            int f = tid + p * 256;
            int k = f >> 5, n = (f & 31) * 4;
            float4 v = *(const float4*)&Bw[(size_t)(k0 + k) * 1024 + n0 + n];
            *(float4*)&bs[k][n] = v;
        }
        __syncthreads();
#pragma unroll
        for (int k = 0; k < 16; ++k) {
            float xv[8], bv[8];
            *(float4*)&xv[0] = *(const float4*)&xs[k][ty * 8];
            *(float4*)&xv[4] = *(const float4*)&xs[k][ty * 8 + 4];
            *(float4*)&bv[0] = *(const float4*)&bs[k][tx * 8];
            *(float4*)&bv[4] = *(const float4*)&bs[k][tx * 8 + 4];
#pragma unroll
            for (int i = 0; i < 8; ++i)
#pragma unroll
                for (int j = 0; j < 8; ++j) acc[i][j] += xv[i] * bv[j];
        }
        __syncthreads();
    }
#pragma unroll
    for (int i = 0; i < 8; ++i)
#pragma unroll
        for (int j = 0; j < 8; j += 4) {
            float4 v = make_float4(acc[i][j], acc[i][j + 1], acc[i][j + 2], acc[i][j + 3]);
            *(float4*)&XB[(size_t)(m0 + ty * 8 + i) * 1024 + n0 + tx * 8 + j] = v;
        }
}

// ---------------------------------------------------------------- group barrier (64 WGs)
// Monotonic counters, relaxed atomics only, NO cache-maintenance fences.
// Ordering: per-wave s_waitcnt vmcnt(0) drains uncached (sc0 sc1) stores to the
// coherence point before arrival; readers use uncached loads -> no inv needed.
__device__ __forceinline__ void group_barrier(unsigned* gf, int sub, int tid, unsigned bar) {
    asm volatile("s_waitcnt vmcnt(0)" ::: "memory");
    __syncthreads();
    if (tid == 0) {
        bool last = false;
        unsigned a = __hip_atomic_fetch_add(gf + (sub << 5), 1u, __ATOMIC_RELAXED, __HIP_MEMORY_SCOPE_AGENT);
        if (a == bar * 8u - 1u) {   // last of 8 WGs in subgroup for this barrier
            unsigned b = __hip_atomic_fetch_add(gf + 256, 1u, __ATOMIC_RELAXED, __HIP_MEMORY_SCOPE_AGENT);
            if (b == bar * 8u - 1u) {   // last of 8 subgroup leaders
                __hip_atomic_store(gf + 288, bar, __ATOMIC_RELAXED, __HIP_MEMORY_SCOPE_AGENT);
                last = true;
            }
        }
        if (!last) {
            while (__hip_atomic_load(gf + 288, __ATOMIC_RELAXED, __HIP_MEMORY_SCOPE_AGENT) < bar)
                __builtin_amdgcn_s_sleep(1);
        }
    }
    __syncthreads();
}

// ---------------------------------------------------------------- persistent scan
// 256 WGs = 4 independent batch-groups x 64 col-slice WGs (16 cols each).
// LDS: A-slice 64KB + CT-slice 64KB (fp32, XOR-swizzled) + h/g staging 32KB = 160KiB.
__global__ __launch_bounds__(NTHR, 1) void scan_kernel(
    const float* __restrict__ A, const float* __restrict__ CTm,
    float* __restrict__ XBH, float* __restrict__ h_buf, float* __restrict__ g_buf,
    float* __restrict__ ht_out, float* __restrict__ ct_out, unsigned* flags) {
    extern __shared__ float lds[];
    float4* a_l  = (float4*)lds;          // [16 cols][256 f4], f4 f stored at f^((f>>4)&7)
    float4* ct_l = a_l + 4096;
    float4* hg_s = ct_l + 4096;           // [8 rows][256 f4], same swizzle

    const int wg = blockIdx.x;
    const int bg = wg >> 6;               // batch group 0..3 (8 batches each)
    const int sg = wg & 63;               // col slice 0..63
    const int c0wg = sg * 16;
    const int tid = threadIdx.x;
    unsigned* gf = flags + (bg << 10);
    const int sub = sg >> 3;

    // ---- one-time weight preload (columns c0wg..c0wg+15 of A and CT) ----
    {
        const int c = tid & 15, i0 = tid >> 4;
        float* al_f  = (float*)a_l;
        float* ctl_f = (float*)ct_l;
        for (int i = i0; i < 1024; i += 32) {
            int p4  = (i >> 2) ^ ((i >> 6) & 7);
            int idx = (c << 10) + (p4 << 2) + (i & 3);
            al_f[idx]  = A[(size_t)i * 1024 + c0wg + c];
            ctl_f[idx] = CTm[(size_t)i * 1024 + c0wg + c];
        }
    }

    // thread mapping (both phases): bp=batch-pair, cp=col-pair, q=k-segment
    const int bp = tid >> 7;              // 0..3  -> batches 2bp, 2bp+1
    const int cp = (tid >> 4) & 7;        // 0..7  -> cols 2cp, 2cp+1
    const int q  = tid & 15;              // 16 k-segments of 64 elems
    const int qs = q & 7;
    const int fb = q << 4;                // f4 base = q*16
    const int s  = q & 3;
    const int gt_i = q >> 2;              // phase-B gate index
    const int bl = 2 * bp + (s & 1);
    const int cl = 2 * cp + (s >> 1);
    const int bglob = bg * 8 + bl;
    const int cglob = c0wg + cl;

    const float* hsrc = h_buf + (size_t)(bg * 8) * 1024;
    const float* gsrc = g_buf + (size_t)(bg * 8) * 1024;

    float creg = 0.f;
    __syncthreads();

    for (int t = 0; t < 512; ++t) {
        // ---------- stage h (uncached, coalesced) into LDS ----------
        {
            const float4* s4 = (const float4*)hsrc;
            float4 v0, v1, v2, v3;
            asm volatile("global_load_dwordx4 %0, %1, off sc0 sc1" : "=v"(v0) : "v"(s4 + tid) : "memory");
            asm volatile("global_load_dwordx4 %0, %1, off sc0 sc1" : "=v"(v1) : "v"(s4 + 512 + tid) : "memory");
            asm volatile("global_load_dwordx4 %0, %1, off sc0 sc1" : "=v"(v2) : "v"(s4 + 1024 + tid) : "memory");
            asm volatile("global_load_dwordx4 %0, %1, off sc0 sc1" : "=v"(v3) : "v"(s4 + 1536 + tid) : "memory");
            asm volatile("s_waitcnt vmcnt(0)" ::: "memory");
            __builtin_amdgcn_sched_barrier(0);
            int u0 = tid, u1 = tid + 512, u2 = tid + 1024, u3 = tid + 1536;
            hg_s[(u0 & ~255) | ((u0 & 255) ^ ((u0 >> 4) & 7))] = v0;
            hg_s[(u1 & ~255) | ((u1 & 255) ^ ((u1 >> 4) & 7))] = v1;
            hg_s[(u2 & ~255) | ((u2 & 255) ^ ((u2 >> 4) & 7))] = v2;
            hg_s[(u3 & ~255) | ((u3 & 255) ^ ((u3 >> 4) & 7))] = v3;
            __syncthreads();
        }
        // ---------- phase A: g[b, c] = (h . A_col) * xb[b,t,c] ----------
        {
            const float4* ac0 = a_l + (cp << 9);
            const float4* ac1 = ac0 + 256;
            const float4* hr0 = hg_s + (bp << 9);
            const float4* hr1 = hr0 + 256;
            float a00 = 0.f, a01 = 0.f, a10 = 0.f, a11 = 0.f;
#pragma unroll
            for (int ii = 0; ii < 16; ++ii) {
                int p = (fb + ii) ^ qs;
                float4 av0 = ac0[p], av1 = ac1[p], hv0 = hr0[p], hv1 = hr1[p];
                a00 += av0.x * hv0.x + av0.y * hv0.y + av0.z * hv0.z + av0.w * hv0.w;
                a01 += av0.x * hv1.x + av0.y * hv1.y + av0.z * hv1.z + av0.w * hv1.w;
                a10 += av1.x * hv0.x + av1.y * hv0.y + av1.z * hv0.z + av1.w * hv0.w;
                a11 += av1.x * hv1.x + av1.y * hv1.y + av1.z * hv1.z + av1.w * hv1.w;
            }
            a00 += __shfl_xor(a00, 1); a00 += __shfl_xor(a00, 2);
            a01 += __shfl_xor(a01, 1); a01 += __shfl_xor(a01, 2);
            a10 += __shfl_xor(a10, 1); a10 += __shfl_xor(a10, 2);
            a11 += __shfl_xor(a11, 1); a11 += __shfl_xor(a11, 2);
            float pown = (q & 2) ? ((q & 1) ? a11 : a10) : ((q & 1) ? a01 : a00);
            pown += __shfl_xor(pown, 4);
            pown += __shfl_xor(pown, 8);
            if (q < 4) {
                float xbv = XBH[((size_t)bglob * 512 + t) * 1024 + cglob];
                st_uc(g_buf + (size_t)bglob * 1024 + cglob, pown * xbv);
            }
        }
        group_barrier(gf, sub, tid, 2 * (unsigned)t + 1u);

        // ---------- stage g into LDS ----------
        {
            const float4* s4 = (const float4*)gsrc;
            float4 v0, v1, v2, v3;
            asm volatile("global_load_dwordx4 %0, %1, off sc0 sc1" : "=v"(v0) : "v"(s4 + tid) : "memory");
            asm volatile("global_load_dwordx4 %0, %1, off sc0 sc1" : "=v"(v1) : "v"(s4 + 512 + tid) : "memory");
            asm volatile("global_load_dwordx4 %0, %1, off sc0 sc1" : "=v"(v2) : "v"(s4 + 1024 + tid) : "memory");
            asm volatile("global_load_dwordx4 %0, %1, off sc0 sc1" : "=v"(v3) : "v"(s4 + 1536 + tid) : "memory");
            asm volatile("s_waitcnt vmcnt(0)" ::: "memory");
            __builtin_amdgcn_sched_barrier(0);
            int u0 = tid, u1 = tid + 512, u2 = tid + 1024, u3 = tid + 1536;
            hg_s[(u0 & ~255) | ((u0 & 255) ^ ((u0 >> 4) & 7))] = v0;
            hg_s[(u1 & ~255) | ((u1 & 255) ^ ((u1 >> 4) & 7))] = v1;
            hg_s[(u2 & ~255) | ((u2 & 255) ^ ((u2 >> 4) & 7))] = v2;
            hg_s[(u3 & ~255) | ((u3 & 255) ^ ((u3 >> 4) & 7))] = v3;
            __syncthreads();
        }
        // ---------- phase B: gates + cell update ----------
        {
            const float4* cc0 = ct_l + (cp << 9);
            const float4* cc1 = cc0 + 256;
            const float4* gr0 = hg_s + (bp << 9);
            const float4* gr1 = gr0 + 256;
            float a00 = 0.f, a01 = 0.f, a10 = 0.f, a11 = 0.f;
#pragma unroll
            for (int ii = 0; ii < 16; ++ii) {
                int p = (fb + ii) ^ qs;
                float4 cv0 = cc0[p], cv1 = cc1[p], gv0 = gr0[p], gv1 = gr1[p];
                a00 += cv0.x * gv0.x + cv0.y * gv0.y + cv0.z * gv0.z + cv0.w * gv0.w;
                a01 += cv0.x * gv1.x + cv0.y * gv1.y + cv0.z * gv1.z + cv0.w * gv1.w;
                a10 += cv1.x * gv0.x + cv1.y * gv0.y + cv1.z * gv0.z + cv1.w * gv0.w;
                a11 += cv1.x * gv1.x + cv1.y * gv1.y + cv1.z * gv1.z + cv1.w * gv1.w;
            }
            // sum the 4 k-segments within this gate (q&3)
            a00 += __shfl_xor(a00, 1); a00 += __shfl_xor(a00, 2);
            a01 += __shfl_xor(a01, 1); a01 += __shfl_xor(a01, 2);
            a10 += __shfl_xor(a10, 1); a10 += __shfl_xor(a10, 2);
            a11 += __shfl_xor(a11, 1); a11 += __shfl_xor(a11, 2);
            float pown = (q & 2) ? ((q & 1) ? a11 : a10) : ((q & 1) ? a01 : a00);
            // gather the 4 gate pre-activations for my (b,j)
            float x = pown;
            float y = __shfl_xor(pown, 4);
            float z = __shfl_xor(pown, 8);
            float w = __shfl_xor(y, 8);
            float pf = (gt_i == 0) ? x : ((gt_i == 1) ? y : ((gt_i == 2) ? z : w));
            float pi = (gt_i == 1) ? x : ((gt_i == 0) ? y : ((gt_i == 3) ? z : w));
            float pg = (gt_i == 2) ? x : ((gt_i == 3) ? y : ((gt_i == 0) ? z : w));
            float po = (gt_i == 3) ? x : ((gt_i == 2) ? y : ((gt_i == 1) ? z : w));
            float ft = 1.f / (1.f + __expf(-pf));
            float it = 1.f / (1.f + __expf(-pi));
            float gg = tanhf(pg);
            float ot = 1.f / (1.f + __expf(-po));
            creg = ft * creg + it * gg;
            float hv = ot * tanhf(creg);
            if (q < 4) {
                st_uc(h_buf + (size_t)bglob * 1024 + cglob, hv);
                st_uc(XBH + ((size_t)bglob * 512 + t) * 1024 + cglob, hv);
                if (t == 511) {
                    st_uc(ht_out + (size_t)bglob * 1024 + cglob, hv);
                    st_uc(ct_out + (size_t)bglob * 1024 + cglob, creg);
                }
            }
        }
        group_barrier(gf, sub, tid, 2 * (unsigned)t + 2u);
    }
}

// ---------------------------------------------------------------- launch
extern "C" void kernel_launch(void* const* d_in, const int* in_sizes, int n_in,
                              void* d_out, int out_size, void* d_ws, size_t ws_size,
                              hipStream_t stream) {
    const float* X   = (const float*)d_in[0];
    const float* A   = (const float*)d_in[1];
    const float* Bw  = (const float*)d_in[2];
    const float* CTm = (const float*)d_in[3];

    float* out    = (float*)d_out;
    float* XBH    = out;                                  // xb in, hidden_seq out
    float* ht_out = out + (size_t)32 * 512 * 1024;
    float* ct_out = ht_out + 32 * 1024;

    float* h_buf = (float*)d_ws;                          // 32 x 1024
    float* g_buf = h_buf + 32 * 1024;                     // 32 x 1024
    unsigned* flags = (unsigned*)(g_buf + 32 * 1024);     // 4 x 1024 uints

    (void)hipFuncSetAttribute((const void*)scan_kernel,
                              hipFuncAttributeMaxDynamicSharedMemorySize, 163840);

    init_kernel<<<dim3(256), dim3(256), 0, stream>>>(h_buf, flags);
    xb_gemm<<<dim3(1024), dim3(256), 0, stream>>>(X, Bw, XBH);
    scan_kernel<<<dim3(256), dim3(NTHR), 163840, stream>>>(A, CTm, XBH, h_buf, g_buf,
                                                           ht_out, ct_out, flags);
}

// Round 3
// 5306.511 us; speedup vs baseline: 4.2313x; 1.0184x over previous
//
#include <hip/hip_runtime.h>
#include <math.h>

#define NTHR 512

// ---------------------------------------------------------------- uncached store
__device__ __forceinline__ void st_uc(float* p, float v) {
    asm volatile("global_store_dword %0, %1, off sc0 sc1" :: "v"(p), "v"(v) : "memory");
}

// ---------------------------------------------------------------- init
__global__ void init_kernel(float* bufs, unsigned* flags) {
    int i = blockIdx.x * blockDim.x + threadIdx.x;
    if (i < 65536) bufs[i] = 0.0f;       // h_buf (32K) + g_buf (32K)
    if (i < 4096) flags[i] = 0u;         // 4 groups x 1024 uints
}

// ---------------------------------------------------------------- xb = x @ b
__global__ __launch_bounds__(256) void xb_gemm(const float* __restrict__ X,
                                               const float* __restrict__ Bw,
                                               float* __restrict__ XB) {
    __shared__ float xs[16][132];
    __shared__ float bs[16][132];
    const int bm = blockIdx.x >> 3;
    const int bn = blockIdx.x & 7;
    const int m0 = bm * 128, n0 = bn * 128;
    const int tid = threadIdx.x;
    const int tx = tid & 15, ty = tid >> 4;
    float acc[8][8];
#pragma unroll
    for (int i = 0; i < 8; ++i)
#pragma unroll
        for (int j = 0; j < 8; ++j) acc[i][j] = 0.f;

    for (int k0 = 0; k0 < 1024; k0 += 16) {
#pragma unroll
        for (int p = 0; p < 2; ++p) {
            int f = tid + p * 256;
            int m = f >> 2, kq = f & 3;
            float4 v = *(const float4*)&X[(size_t)(m0 + m) * 1024 + k0 + kq * 4];
            xs[kq * 4 + 0][m] = v.x; xs[kq * 4 + 1][m] = v.y;
            xs[kq * 4 + 2][m] = v.z; xs[kq * 4 + 3][m] = v.w;
        }
#pragma unroll
        for (int p = 0; p < 2; ++p) {
            int f = tid + p * 256;
            int k = f >> 5, n = (f & 31) * 4;
            float4 v = *(const float4*)&Bw[(size_t)(k0 + k) * 1024 + n0 + n];
            *(float4*)&bs[k][n] = v;
        }
        __syncthreads();
#pragma unroll
        for (int k = 0; k < 16; ++k) {
            float xv[8], bv[8];
            *(float4*)&xv[0] = *(const float4*)&xs[k][ty * 8];
            *(float4*)&xv[4] = *(const float4*)&xs[k][ty * 8 + 4];
            *(float4*)&bv[0] = *(const float4*)&bs[k][tx * 8];
            *(float4*)&bv[4] = *(const float4*)&bs[k][tx * 8 + 4];
#pragma unroll
            for (int i = 0; i < 8; ++i)
#pragma unroll
                for (int j = 0; j < 8; ++j) acc[i][j] += xv[i] * bv[j];
        }
        __syncthreads();
    }
#pragma unroll
    for (int i = 0; i < 8; ++i)
#pragma unroll
        for (int j = 0; j < 8; j += 4) {
            float4 v = make_float4(acc[i][j], acc[i][j + 1], acc[i][j + 2], acc[i][j + 3]);
            *(float4*)&XB[(size_t)(m0 + ty * 8 + i) * 1024 + n0 + tx * 8 + j] = v;
        }
}

// ---------------------------------------------------------------- group barrier (64 WGs)
__device__ __forceinline__ void group_barrier(unsigned* gf, int sub, int tid, unsigned bar) {
    asm volatile("s_waitcnt vmcnt(0)" ::: "memory");
    __syncthreads();
    if (tid == 0) {
        bool last = false;
        unsigned a = __hip_atomic_fetch_add(gf + (sub << 5), 1u, __ATOMIC_RELAXED, __HIP_MEMORY_SCOPE_AGENT);
        if (a == bar * 8u - 1u) {
            unsigned b = __hip_atomic_fetch_add(gf + 256, 1u, __ATOMIC_RELAXED, __HIP_MEMORY_SCOPE_AGENT);
            if (b == bar * 8u - 1u) {
                __hip_atomic_store(gf + 288, bar, __ATOMIC_RELAXED, __HIP_MEMORY_SCOPE_AGENT);
                last = true;
            }
        }
        if (!last) {
            while (__hip_atomic_load(gf + 288, __ATOMIC_RELAXED, __HIP_MEMORY_SCOPE_AGENT) < bar)
                __builtin_amdgcn_s_sleep(1);
        }
    }
    __syncthreads();
}

// ---------------------------------------------------------------- persistent scan
// 256 WGs = 4 batch-groups (8 batches) x 64 col-slices (16 cols).
// LDS: A cols 64KB + CT cols 64KB + h/g staging 32KB (scr 2KB aliased) = 160KiB.
// Wave w phase A: col-group w&1 (8 cols), K-quarter w>>1 (f4 kq*64+L, 1 f4/lane).
// Wave w phase B: col-group w&1, gate w>>1 (f4 g*64+L covers the gate's full 256 rows).
// Lane loads are XOR-permuted (row r^Lb, col c^Lc) so slot m holds out[m^L];
// butterfly v[j]=v[2j]+shfl_xor(v[2j+1],d) then leaves out[L] in lane L, select-free.
__global__ __launch_bounds__(NTHR, 1) void scan_kernel(
    const float* __restrict__ A, const float* __restrict__ CTm,
    float* __restrict__ XBH, float* __restrict__ h_buf, float* __restrict__ g_buf,
    float* __restrict__ ht_out, float* __restrict__ ct_out, unsigned* flags) {
    extern __shared__ float lds[];
    float* a_lf  = lds;                   // [16 cols][1024] col-major
    float* ct_lf = lds + 16384;           // [16 cols][1024]
    float* hg_f  = lds + 32768;           // [8 rows][1024] staging; scr aliases head
    float4* a_l4  = (float4*)a_lf;
    float4* ct_l4 = (float4*)ct_lf;
    float4* hg_4  = (float4*)hg_f;
    float* scr = hg_f;                    // 512 floats, used only between syncs

    const int wg = blockIdx.x;
    const int bg = wg >> 6;
    const int sg = wg & 63;
    const int c0wg = sg * 16;
    const int tid = threadIdx.x;
    unsigned* gf = flags + (bg << 10);
    const int sub = sg >> 3;

    // ---- one-time weight preload: columns c0wg..c0wg+15, linear col-major ----
    {
        const int c = tid & 15, i0 = tid >> 4;
        for (int i = i0; i < 1024; i += 32) {
            a_lf[c * 1024 + i]  = A[(size_t)i * 1024 + c0wg + c];
            ct_lf[c * 1024 + i] = CTm[(size_t)i * 1024 + c0wg + c];
        }
    }

    const int L  = tid & 63;
    const int w  = tid >> 6;
    const int Lc = L & 7;
    const int Lb = (L >> 3) & 7;
    const int cgA = w & 1, kqA = w >> 1;
    const int gB  = w >> 1;               // phase-B gate (col-group same w&1)

    int hIdx[8], aIdx[8], gIdx[8], cIdx[8];
#pragma unroll
    for (int r = 0; r < 8; ++r) hIdx[r] = (r ^ Lb) * 256 + kqA * 64 + L;
#pragma unroll
    for (int c = 0; c < 8; ++c) aIdx[c] = (cgA * 8 + (c ^ Lc)) * 256 + kqA * 64 + L;
#pragma unroll
    for (int r = 0; r < 8; ++r) gIdx[r] = (r ^ Lb) * 256 + gB * 64 + L;
#pragma unroll
    for (int c = 0; c < 8; ++c) cIdx[c] = (cgA * 8 + (c ^ Lc)) * 256 + gB * 64 + L;

    // epilogue mapping (tid < 128): one (batch, col) pair each
    const int e_b  = tid >> 4;
    const int e_j  = tid & 15;
    const int e_cg = e_j >> 3;
    const int e_slot = e_b * 8 + (e_j & 7);
    const int e_bglob = bg * 8 + e_b;
    const int e_col   = c0wg + e_j;

    const float4* hsrc4 = (const float4*)(h_buf + (size_t)bg * 8192);
    const float4* gsrc4 = (const float4*)(g_buf + (size_t)bg * 8192);

    float creg = 0.f;
    unsigned barc = 0;
    __syncthreads();   // weights ready

    for (int t = 0; t < 512; ++t) {
        // xb prefetch (normal cached load; line is exclusively ours this step)
        float xbv = 0.f;
        if (tid < 128) xbv = XBH[((size_t)e_bglob * 512 + t) * 1024 + e_col];

        // ---------- stage h (uncached, coalesced, linear LDS) ----------
        {
            float4 v0, v1, v2, v3;
            asm volatile("global_load_dwordx4 %0, %1, off sc0 sc1" : "=v"(v0) : "v"(hsrc4 + tid) : "memory");
            asm volatile("global_load_dwordx4 %0, %1, off sc0 sc1" : "=v"(v1) : "v"(hsrc4 + 512 + tid) : "memory");
            asm volatile("global_load_dwordx4 %0, %1, off sc0 sc1" : "=v"(v2) : "v"(hsrc4 + 1024 + tid) : "memory");
            asm volatile("global_load_dwordx4 %0, %1, off sc0 sc1" : "=v"(v3) : "v"(hsrc4 + 1536 + tid) : "memory");
            asm volatile("s_waitcnt vmcnt(0)" ::: "memory");
            __builtin_amdgcn_sched_barrier(0);
            hg_4[tid] = v0; hg_4[512 + tid] = v1; hg_4[1024 + tid] = v2; hg_4[1536 + tid] = v3;
            __syncthreads();
        }
        // ---------- phase A: 64 dot4s, one f4 per (r,c), then butterfly ----------
        float v[64];
        {
            float4 hv[8], av[8];
#pragma unroll
            for (int r = 0; r < 8; ++r) hv[r] = hg_4[hIdx[r]];
#pragma unroll
            for (int c = 0; c < 8; ++c) av[c] = a_l4[aIdx[c]];
#pragma unroll
            for (int r = 0; r < 8; ++r)
#pragma unroll
                for (int c = 0; c < 8; ++c)
                    v[r * 8 + c] = hv[r].x * av[c].x + hv[r].y * av[c].y
                                 + hv[r].z * av[c].z + hv[r].w * av[c].w;
        }
#pragma unroll
        for (int j = 0; j < 32; ++j) v[j] = v[2 * j] + __shfl_xor(v[2 * j + 1], 1);
#pragma unroll
        for (int j = 0; j < 16; ++j) v[j] = v[2 * j] + __shfl_xor(v[2 * j + 1], 2);
#pragma unroll
        for (int j = 0; j < 8; ++j)  v[j] = v[2 * j] + __shfl_xor(v[2 * j + 1], 4);
#pragma unroll
        for (int j = 0; j < 4; ++j)  v[j] = v[2 * j] + __shfl_xor(v[2 * j + 1], 8);
#pragma unroll
        for (int j = 0; j < 2; ++j)  v[j] = v[2 * j] + __shfl_xor(v[2 * j + 1], 16);
        v[0] = v[0] + __shfl_xor(v[1], 32);

        __syncthreads();                      // all hg reads done (scr aliases hg)
        scr[w * 64 + L] = v[0];
        __syncthreads();
        if (tid < 128) {
            float s = scr[(0 * 2 + e_cg) * 64 + e_slot] + scr[(1 * 2 + e_cg) * 64 + e_slot]
                    + scr[(2 * 2 + e_cg) * 64 + e_slot] + scr[(3 * 2 + e_cg) * 64 + e_slot];
            st_uc(g_buf + (size_t)e_bglob * 1024 + e_col, s * xbv);
        }
        group_barrier(gf, sub, tid, ++barc);

        // ---------- stage g ----------
        {
            float4 v0, v1, v2, v3;
            asm volatile("global_load_dwordx4 %0, %1, off sc0 sc1" : "=v"(v0) : "v"(gsrc4 + tid) : "memory");
            asm volatile("global_load_dwordx4 %0, %1, off sc0 sc1" : "=v"(v1) : "v"(gsrc4 + 512 + tid) : "memory");
            asm volatile("global_load_dwordx4 %0, %1, off sc0 sc1" : "=v"(v2) : "v"(gsrc4 + 1024 + tid) : "memory");
            asm volatile("global_load_dwordx4 %0, %1, off sc0 sc1" : "=v"(v3) : "v"(gsrc4 + 1536 + tid) : "memory");
            asm volatile("s_waitcnt vmcnt(0)" ::: "memory");
            __builtin_amdgcn_sched_barrier(0);
            hg_4[tid] = v0; hg_4[512 + tid] = v1; hg_4[1024 + tid] = v2; hg_4[1536 + tid] = v3;
            __syncthreads();
        }
        // ---------- phase B: each wave completes its gate's full dot ----------
        {
            float4 gv[8], cv[8];
#pragma unroll
            for (int r = 0; r < 8; ++r) gv[r] = hg_4[gIdx[r]];
#pragma unroll
            for (int c = 0; c < 8; ++c) cv[c] = ct_l4[cIdx[c]];
#pragma unroll
            for (int r = 0; r < 8; ++r)
#pragma unroll
                for (int c = 0; c < 8; ++c)
                    v[r * 8 + c] = gv[r].x * cv[c].x + gv[r].y * cv[c].y
                                 + gv[r].z * cv[c].z + gv[r].w * cv[c].w;
        }
#pragma unroll
        for (int j = 0; j < 32; ++j) v[j] = v[2 * j] + __shfl_xor(v[2 * j + 1], 1);
#pragma unroll
        for (int j = 0; j < 16; ++j) v[j] = v[2 * j] + __shfl_xor(v[2 * j + 1], 2);
#pragma unroll
        for (int j = 0; j < 8; ++j)  v[j] = v[2 * j] + __shfl_xor(v[2 * j + 1], 4);
#pragma unroll
        for (int j = 0; j < 4; ++j)  v[j] = v[2 * j] + __shfl_xor(v[2 * j + 1], 8);
#pragma unroll
        for (int j = 0; j < 2; ++j)  v[j] = v[2 * j] + __shfl_xor(v[2 * j + 1], 16);
        v[0] = v[0] + __shfl_xor(v[1], 32);

        __syncthreads();
        scr[w * 64 + L] = v[0];
        __syncthreads();
        if (tid < 128) {
            float pf = scr[(0 * 2 + e_cg) * 64 + e_slot];
            float pi = scr[(1 * 2 + e_cg) * 64 + e_slot];
            float pg = scr[(2 * 2 + e_cg) * 64 + e_slot];
            float po = scr[(3 * 2 + e_cg) * 64 + e_slot];
            float ft = 1.f / (1.f + __expf(-pf));
            float it = 1.f / (1.f + __expf(-pi));
            float gt = tanhf(pg);
            float ot = 1.f / (1.f + __expf(-po));
            creg = ft * creg + it * gt;
            float hv2 = ot * tanhf(creg);
            st_uc(h_buf + (size_t)e_bglob * 1024 + e_col, hv2);
            st_uc(XBH + ((size_t)e_bglob * 512 + t) * 1024 + e_col, hv2);
            if (t == 511) {
                st_uc(ht_out + (size_t)e_bglob * 1024 + e_col, hv2);
                st_uc(ct_out + (size_t)e_bglob * 1024 + e_col, creg);
            }
        }
        group_barrier(gf, sub, tid, ++barc);
    }
}

// ---------------------------------------------------------------- launch
extern "C" void kernel_launch(void* const* d_in, const int* in_sizes, int n_in,
                              void* d_out, int out_size, void* d_ws, size_t ws_size,
                              hipStream_t stream) {
    const float* X   = (const float*)d_in[0];
    const float* A   = (const float*)d_in[1];
    const float* Bw  = (const float*)d_in[2];
    const float* CTm = (const float*)d_in[3];

    float* out    = (float*)d_out;
    float* XBH    = out;                                  // xb in, hidden_seq out
    float* ht_out = out + (size_t)32 * 512 * 1024;
    float* ct_out = ht_out + 32 * 1024;

    float* h_buf = (float*)d_ws;                          // 32 x 1024
    float* g_buf = h_buf + 32 * 1024;                     // 32 x 1024
    unsigned* flags = (unsigned*)(g_buf + 32 * 1024);     // 4 x 1024 uints

    (void)hipFuncSetAttribute((const void*)scan_kernel,
                              hipFuncAttributeMaxDynamicSharedMemorySize, 163840);

    init_kernel<<<dim3(256), dim3(256), 0, stream>>>(h_buf, flags);
    xb_gemm<<<dim3(1024), dim3(256), 0, stream>>>(X, Bw, XBH);
    scan_kernel<<<dim3(256), dim3(NTHR), 163840, stream>>>(A, CTm, XBH, h_buf, g_buf,
                                                           ht_out, ct_out, flags);
}